// Round 1
// baseline (3025.192 us; speedup 1.0000x reference)
//
#include <hip/hip_runtime.h>

#define D 128

// ---------------- zero fill ----------------
__global__ __launch_bounds__(256) void zero_kernel(float4* __restrict__ p, int n4) {
    int i = blockIdx.x * blockDim.x + threadIdx.x;
    int stride = gridDim.x * blockDim.x;
    for (; i < n4; i += stride) p[i] = make_float4(0.f, 0.f, 0.f, 0.f);
}

// ---------------- degree histogram ----------------
__global__ __launch_bounds__(256) void deg_kernel(const int* __restrict__ dst,
                                                  float* __restrict__ deg, int E) {
    int e = blockIdx.x * blockDim.x + threadIdx.x;
    if (e < E) atomicAdd(&deg[dst[e]], 1.0f);
}

// ---------------- scatter-add: agg[dst] += feat[src] ----------------
// one thread = one (edge, 4-channel group); 32 threads per edge
__global__ __launch_bounds__(256) void scatter_kernel(const float* __restrict__ feat,
                                                      const int* __restrict__ src,
                                                      const int* __restrict__ dst,
                                                      float* __restrict__ agg, int E) {
    int idx = blockIdx.x * blockDim.x + threadIdx.x;
    if (idx >= E * 32) return;
    int e = idx >> 5;
    int c = (idx & 31) * 4;
    int s = src[e];
    int d = dst[e];
    const float4 v = *(const float4*)(feat + (size_t)s * D + c);
    float* p = agg + (size_t)d * D + c;
    atomicAdd(p + 0, v.x);
    atomicAdd(p + 1, v.y);
    atomicAdd(p + 2, v.z);
    atomicAdd(p + 3, v.w);
}

// ---------------- fused (agg/deg)@Wl + x@Wr + b (+relu) ----------------
// 32 nodes per block, 256 threads: thread -> (4 nodes) x (4 channels)
#define BN 32
__global__ __launch_bounds__(256) void sage_gemm(const float* __restrict__ agg,
                                                 const float* __restrict__ deg,
                                                 const float* __restrict__ x,
                                                 const float* __restrict__ Wl,
                                                 const float* __restrict__ Wr,
                                                 const float* __restrict__ bias,
                                                 float* __restrict__ out,
                                                 int n_nodes, int do_relu) {
    __shared__ float a_sh[BN][D];
    __shared__ float x_sh[BN][D];
    __shared__ float wl_sh[16][D];
    __shared__ float wr_sh[16][D];

    const int tid = threadIdx.x;
    const int n0 = blockIdx.x * BN;

    // stage 32 node rows (agg scaled by 1/max(deg,1), and x)
    for (int i = tid; i < BN * (D / 4); i += 256) {
        int row = i / (D / 4);
        int col = (i % (D / 4)) * 4;
        int n = n0 + row;
        float4 av = make_float4(0.f, 0.f, 0.f, 0.f);
        float4 xv = av;
        float dinv = 0.f;
        if (n < n_nodes) {
            av = *(const float4*)(agg + (size_t)n * D + col);
            xv = *(const float4*)(x + (size_t)n * D + col);
            dinv = 1.0f / fmaxf(deg[n], 1.0f);
        }
        av.x *= dinv; av.y *= dinv; av.z *= dinv; av.w *= dinv;
        *(float4*)&a_sh[row][col] = av;
        *(float4*)&x_sh[row][col] = xv;
    }

    float acc[4][4];
#pragma unroll
    for (int j = 0; j < 4; ++j)
#pragma unroll
        for (int m = 0; m < 4; ++m) acc[j][m] = 0.f;

    const int c  = (tid & 31) * 4;   // output channel group
    const int nb = (tid >> 5) * 4;   // local node group

    for (int k0 = 0; k0 < D; k0 += 16) {
        __syncthreads();
        // stage 16xD tiles of both weight matrices
        for (int i = tid; i < 16 * (D / 4); i += 256) {
            int kk = i / (D / 4);
            int cc = (i % (D / 4)) * 4;
            *(float4*)&wl_sh[kk][cc] = *(const float4*)(Wl + (size_t)(k0 + kk) * D + cc);
            *(float4*)&wr_sh[kk][cc] = *(const float4*)(Wr + (size_t)(k0 + kk) * D + cc);
        }
        __syncthreads();
#pragma unroll
        for (int k = 0; k < 16; ++k) {
            float4 wl = *(float4*)&wl_sh[k][c];
            float4 wr = *(float4*)&wr_sh[k][c];
#pragma unroll
            for (int j = 0; j < 4; ++j) {
                float a = a_sh[nb + j][k0 + k];
                float xx = x_sh[nb + j][k0 + k];
                acc[j][0] += a * wl.x + xx * wr.x;
                acc[j][1] += a * wl.y + xx * wr.y;
                acc[j][2] += a * wl.z + xx * wr.z;
                acc[j][3] += a * wl.w + xx * wr.w;
            }
        }
    }

    float4 bv = *(const float4*)(bias + c);
#pragma unroll
    for (int j = 0; j < 4; ++j) {
        int n = n0 + nb + j;
        if (n >= n_nodes) continue;
        float4 r;
        r.x = acc[j][0] + bv.x;
        r.y = acc[j][1] + bv.y;
        r.z = acc[j][2] + bv.z;
        r.w = acc[j][3] + bv.w;
        if (do_relu) {
            r.x = fmaxf(r.x, 0.f); r.y = fmaxf(r.y, 0.f);
            r.z = fmaxf(r.z, 0.f); r.w = fmaxf(r.w, 0.f);
        }
        *(float4*)(out + (size_t)n * D + c) = r;
    }
}

// ---------------- edge dot-product decode ----------------
// 32 lanes per pred-edge, float4 per lane, shuffle reduce
__global__ __launch_bounds__(256) void pred_kernel(const float* __restrict__ z,
                                                   const int* __restrict__ ps,
                                                   const int* __restrict__ pd,
                                                   float* __restrict__ out, int EP) {
    int idx = blockIdx.x * blockDim.x + threadIdx.x;
    int e = idx >> 5;
    if (e >= EP) return;
    int l = idx & 31;
    int a = ps[e];
    int b = pd[e];
    float4 va = *(const float4*)(z + (size_t)a * D + l * 4);
    float4 vb = *(const float4*)(z + (size_t)b * D + l * 4);
    float p = va.x * vb.x + va.y * vb.y + va.z * vb.z + va.w * vb.w;
#pragma unroll
    for (int off = 16; off > 0; off >>= 1) p += __shfl_xor(p, off, 32);
    if (l == 0) out[e] = p;
}

extern "C" void kernel_launch(void* const* d_in, const int* in_sizes, int n_in,
                              void* d_out, int out_size, void* d_ws, size_t ws_size,
                              hipStream_t stream) {
    const float* x   = (const float*)d_in[0];
    const float* W1l = (const float*)d_in[1];
    const float* b1  = (const float*)d_in[2];
    const float* W1r = (const float*)d_in[3];
    const float* W2l = (const float*)d_in[4];
    const float* b2  = (const float*)d_in[5];
    const float* W2r = (const float*)d_in[6];
    const int* edge_index = (const int*)d_in[7];
    const int* pred_edges = (const int*)d_in[8];
    float* out = (float*)d_out;

    const int N  = in_sizes[0] / D;       // 50000
    const int E  = in_sizes[7] / 2;       // 800000
    const int EP = in_sizes[8] / 2;       // 200000

    const int* src = edge_index;
    const int* dst = edge_index + E;
    const int* ps  = pred_edges;
    const int* pd  = pred_edges + EP;

    // workspace layout (floats): deg | agg | h | z
    float* ws = (float*)d_ws;
    const size_t degN  = 50048;                  // padded
    const size_t rowsN = (size_t)N * D;
    float* deg = ws;
    float* agg = ws + degN;
    float* h   = agg + rowsN;
    float* z   = h + rowsN;

    const int nz4 = (int)((degN + rowsN) / 4);   // zero deg+agg together
    const int na4 = (int)(rowsN / 4);

    // layer 1
    zero_kernel<<<6400, 256, 0, stream>>>((float4*)deg, nz4);
    deg_kernel<<<(E + 255) / 256, 256, 0, stream>>>(dst, deg, E);
    scatter_kernel<<<(E * 32 + 255) / 256, 256, 0, stream>>>(x, src, dst, agg, E);
    sage_gemm<<<(N + BN - 1) / BN, 256, 0, stream>>>(agg, deg, x, W1l, W1r, b1, h, N, 1);

    // layer 2
    zero_kernel<<<6400, 256, 0, stream>>>((float4*)agg, na4);
    scatter_kernel<<<(E * 32 + 255) / 256, 256, 0, stream>>>(h, src, dst, agg, E);
    sage_gemm<<<(N + BN - 1) / BN, 256, 0, stream>>>(agg, deg, h, W2l, W2r, b2, z, N, 0);

    // decode
    pred_kernel<<<(EP * 32 + 255) / 256, 256, 0, stream>>>(z, ps, pd, out, EP);
}

// Round 2
// 746.610 us; speedup vs baseline: 4.0519x; 4.0519x over previous
//
#include <hip/hip_runtime.h>

#define D 128
#define BN 32   // nodes per sage block

// ---------------- zero int fill ----------------
__global__ __launch_bounds__(256) void zero_int_kernel(int* __restrict__ p, int n) {
    int i = blockIdx.x * blockDim.x + threadIdx.x;
    if (i < n) p[i] = 0;
}

// ---------------- degree histogram into cnt ----------------
__global__ __launch_bounds__(256) void hist_kernel(const int* __restrict__ dst,
                                                   int* __restrict__ cnt, int E) {
    int e = blockIdx.x * blockDim.x + threadIdx.x;
    if (e < E) atomicAdd(&cnt[dst[e]], 1);
}

// ---------------- single-block scan: off[i]=excl prefix, cursor[i]=off[i] ----------------
__global__ __launch_bounds__(1024) void scan_kernel(const int* __restrict__ cnt,
                                                    int* __restrict__ off,
                                                    int* __restrict__ cursor, int n) {
    __shared__ int wsum[16];
    __shared__ int carry_sh;
    const int tid = threadIdx.x;
    const int lane = tid & 63;
    const int wv = tid >> 6;
    if (tid == 0) { carry_sh = 0; off[0] = 0; }
    __syncthreads();
    for (int base = 0; base < n; base += 1024) {
        int i = base + tid;
        int v = (i < n) ? cnt[i] : 0;
        int s = v;  // inclusive scan within wave
#pragma unroll
        for (int o = 1; o < 64; o <<= 1) {
            int t = __shfl_up(s, o, 64);
            if (lane >= o) s += t;
        }
        if (lane == 63) wsum[wv] = s;
        __syncthreads();
        if (wv == 0 && lane < 16) {
            int t = wsum[lane];
#pragma unroll
            for (int o = 1; o < 16; o <<= 1) {
                int u = __shfl_up(t, o, 64);
                if (lane >= o) t += u;
            }
            wsum[lane] = t;
        }
        __syncthreads();
        int add = carry_sh + (wv > 0 ? wsum[wv - 1] : 0);
        int total = wsum[15];
        if (i < n) {
            off[i + 1] = s + add;          // inclusive end
            cursor[i] = s + add - v;       // exclusive start
        }
        __syncthreads();
        if (tid == 0) carry_sh += total;
        __syncthreads();
    }
}

// ---------------- bucket fill: csr_src[pos] = src, sorted by dst ----------------
__global__ __launch_bounds__(256) void bucket_kernel(const int* __restrict__ src,
                                                     const int* __restrict__ dst,
                                                     int* __restrict__ cursor,
                                                     int* __restrict__ csr_src, int E) {
    int e = blockIdx.x * blockDim.x + threadIdx.x;
    if (e >= E) return;
    int pos = atomicAdd(&cursor[dst[e]], 1);
    csr_src[pos] = src[e];
}

// ---------------- fused gather-mean + (mean@Wl + x@Wr + b) (+relu) ----------------
// 32 nodes per block, 256 threads (4 waves). Phase A: each wave gathers 8 nodes'
// neighbor rows (lane = 2 channels, float2) into a_sh, and stages x rows into x_sh.
// Phase B: register-tiled GEMM, thread -> (4 nodes) x (4 channels).
__global__ __launch_bounds__(256) void sage_fused(const float* __restrict__ feat,
                                                  const int* __restrict__ off,
                                                  const int* __restrict__ csr_src,
                                                  const float* __restrict__ Wl,
                                                  const float* __restrict__ Wr,
                                                  const float* __restrict__ bias,
                                                  float* __restrict__ out,
                                                  int n_nodes, int do_relu) {
    __shared__ float a_sh[BN][D];
    __shared__ float x_sh[BN][D];
    __shared__ float wl_sh[16][D];
    __shared__ float wr_sh[16][D];

    const int tid = threadIdx.x;
    const int lane = tid & 63;
    const int wv = tid >> 6;
    const int n0 = blockIdx.x * BN;

    // stage x rows (coalesced float4)
    for (int i = tid; i < BN * (D / 4); i += 256) {
        int row = i / (D / 4);
        int col = (i % (D / 4)) * 4;
        int n = n0 + row;
        float4 xv = make_float4(0.f, 0.f, 0.f, 0.f);
        if (n < n_nodes) xv = *(const float4*)(feat + (size_t)n * D + col);
        *(float4*)&x_sh[row][col] = xv;
    }

    // gather-mean: wave wv handles local nodes wv*8 .. wv*8+7
    for (int j = wv * 8; j < wv * 8 + 8; ++j) {
        int n = n0 + j;
        float2 acc = make_float2(0.f, 0.f);
        if (n < n_nodes) {
            int start = off[n];
            int end = off[n + 1];
            int e = start;
            for (; e + 1 < end; e += 2) {  // 2x ILP
                int s0 = csr_src[e];
                int s1 = csr_src[e + 1];
                float2 v0 = *(const float2*)(feat + (size_t)s0 * D + lane * 2);
                float2 v1 = *(const float2*)(feat + (size_t)s1 * D + lane * 2);
                acc.x += v0.x + v1.x;
                acc.y += v0.y + v1.y;
            }
            if (e < end) {
                int s0 = csr_src[e];
                float2 v0 = *(const float2*)(feat + (size_t)s0 * D + lane * 2);
                acc.x += v0.x;
                acc.y += v0.y;
            }
            float dinv = 1.0f / fmaxf((float)(end - start), 1.0f);
            acc.x *= dinv;
            acc.y *= dinv;
        }
        *(float2*)&a_sh[j][lane * 2] = acc;
    }

    float accr[4][4];
#pragma unroll
    for (int j = 0; j < 4; ++j)
#pragma unroll
        for (int m = 0; m < 4; ++m) accr[j][m] = 0.f;

    const int c = (tid & 31) * 4;    // output channel group
    const int nb = (tid >> 5) * 4;   // local node group

    for (int k0 = 0; k0 < D; k0 += 16) {
        __syncthreads();
        for (int i = tid; i < 16 * (D / 4); i += 256) {
            int kk = i / (D / 4);
            int cc = (i % (D / 4)) * 4;
            *(float4*)&wl_sh[kk][cc] = *(const float4*)(Wl + (size_t)(k0 + kk) * D + cc);
            *(float4*)&wr_sh[kk][cc] = *(const float4*)(Wr + (size_t)(k0 + kk) * D + cc);
        }
        __syncthreads();
#pragma unroll
        for (int k = 0; k < 16; ++k) {
            float4 wl = *(float4*)&wl_sh[k][c];
            float4 wr = *(float4*)&wr_sh[k][c];
#pragma unroll
            for (int j = 0; j < 4; ++j) {
                float a = a_sh[nb + j][k0 + k];
                float xx = x_sh[nb + j][k0 + k];
                accr[j][0] += a * wl.x + xx * wr.x;
                accr[j][1] += a * wl.y + xx * wr.y;
                accr[j][2] += a * wl.z + xx * wr.z;
                accr[j][3] += a * wl.w + xx * wr.w;
            }
        }
    }

    float4 bv = *(const float4*)(bias + c);
#pragma unroll
    for (int j = 0; j < 4; ++j) {
        int n = n0 + nb + j;
        if (n >= n_nodes) continue;
        float4 r;
        r.x = accr[j][0] + bv.x;
        r.y = accr[j][1] + bv.y;
        r.z = accr[j][2] + bv.z;
        r.w = accr[j][3] + bv.w;
        if (do_relu) {
            r.x = fmaxf(r.x, 0.f); r.y = fmaxf(r.y, 0.f);
            r.z = fmaxf(r.z, 0.f); r.w = fmaxf(r.w, 0.f);
        }
        *(float4*)(out + (size_t)n * D + c) = r;
    }
}

// ---------------- edge dot-product decode ----------------
__global__ __launch_bounds__(256) void pred_kernel(const float* __restrict__ z,
                                                   const int* __restrict__ ps,
                                                   const int* __restrict__ pd,
                                                   float* __restrict__ out, int EP) {
    int idx = blockIdx.x * blockDim.x + threadIdx.x;
    int e = idx >> 5;
    if (e >= EP) return;
    int l = idx & 31;
    int a = ps[e];
    int b = pd[e];
    float4 va = *(const float4*)(z + (size_t)a * D + l * 4);
    float4 vb = *(const float4*)(z + (size_t)b * D + l * 4);
    float p = va.x * vb.x + va.y * vb.y + va.z * vb.z + va.w * vb.w;
#pragma unroll
    for (int off = 16; off > 0; off >>= 1) p += __shfl_xor(p, off, 32);
    if (l == 0) out[e] = p;
}

extern "C" void kernel_launch(void* const* d_in, const int* in_sizes, int n_in,
                              void* d_out, int out_size, void* d_ws, size_t ws_size,
                              hipStream_t stream) {
    const float* x   = (const float*)d_in[0];
    const float* W1l = (const float*)d_in[1];
    const float* b1  = (const float*)d_in[2];
    const float* W1r = (const float*)d_in[3];
    const float* W2l = (const float*)d_in[4];
    const float* b2  = (const float*)d_in[5];
    const float* W2r = (const float*)d_in[6];
    const int* edge_index = (const int*)d_in[7];
    const int* pred_edges = (const int*)d_in[8];
    float* out = (float*)d_out;

    const int N  = in_sizes[0] / D;       // 50000
    const int E  = in_sizes[7] / 2;       // 800000
    const int EP = in_sizes[8] / 2;       // 200000

    const int* src = edge_index;
    const int* dst = edge_index + E;
    const int* ps  = pred_edges;
    const int* pd  = pred_edges + EP;

    // workspace layout: off[N+1] | cursor[N] | csr_src[E] | h[N*D] | z[N*D]
    int* off     = (int*)d_ws;
    int* cursor  = off + (N + 1);
    int* csr_src = cursor + N;
    float* h     = (float*)(csr_src + E);
    float* z     = h + (size_t)N * D;

    const int nblk_sage = (N + BN - 1) / BN;

    // build CSR (cnt accumulated in cursor, then scan rewrites it to start offsets)
    zero_int_kernel<<<(N + 255) / 256, 256, 0, stream>>>(cursor, N);
    hist_kernel<<<(E + 255) / 256, 256, 0, stream>>>(dst, cursor, E);
    scan_kernel<<<1, 1024, 0, stream>>>(cursor, off, cursor, N);
    bucket_kernel<<<(E + 255) / 256, 256, 0, stream>>>(src, dst, cursor, csr_src, E);

    // layer 1: h = relu(mean@W1l + x@W1r + b1)
    sage_fused<<<nblk_sage, 256, 0, stream>>>(x, off, csr_src, W1l, W1r, b1, h, N, 1);
    // layer 2: z = mean@W2l + h@W2r + b2
    sage_fused<<<nblk_sage, 256, 0, stream>>>(h, off, csr_src, W2l, W2r, b2, z, N, 0);
    // decode
    pred_kernel<<<(EP * 32 + 255) / 256, 256, 0, stream>>>(z, ps, pd, out, EP);
}

// Round 3
// 445.853 us; speedup vs baseline: 6.7852x; 1.6746x over previous
//
#include <hip/hip_runtime.h>

#define D 128
#define NPW 16           // nodes per wave (MFMA tile M)
#define WPB 4            // waves per block
#define BN (NPW * WPB)   // 64 nodes per block
#define AST 132          // a_sh padded k-stride (2-way-only bank conflicts)

typedef __attribute__((ext_vector_type(8))) short short8;
typedef __attribute__((ext_vector_type(4))) float f32x4;

// fp32 -> bf16 bits, round-to-nearest-even
__device__ inline unsigned int f2bf_bits(float f) {
    unsigned int u = __float_as_uint(f);
    return (u + 0x7FFFu + ((u >> 16) & 1u)) >> 16;
}

// ---------------- zero int fill ----------------
__global__ __launch_bounds__(256) void zero_int_kernel(int* __restrict__ p, int n) {
    int i = blockIdx.x * blockDim.x + threadIdx.x;
    if (i < n) p[i] = 0;
}

// ---------------- degree histogram ----------------
__global__ __launch_bounds__(256) void hist_kernel(const int* __restrict__ dst,
                                                   int* __restrict__ cnt, int E) {
    int e = blockIdx.x * blockDim.x + threadIdx.x;
    if (e < E) atomicAdd(&cnt[dst[e]], 1);
}

// ---------------- hierarchical scan: 1024 elements per block ----------------
__global__ __launch_bounds__(256) void scan1_kernel(const int* __restrict__ cnt,
                                                    int* __restrict__ partial, int n) {
    __shared__ int ws[4];
    int t = threadIdx.x;
    int base = blockIdx.x * 1024 + t * 4;
    int s = 0;
#pragma unroll
    for (int i = 0; i < 4; ++i)
        if (base + i < n) s += cnt[base + i];
#pragma unroll
    for (int o = 1; o < 64; o <<= 1) s += __shfl_xor(s, o, 64);
    if ((t & 63) == 0) ws[t >> 6] = s;
    __syncthreads();
    if (t == 0) partial[blockIdx.x] = ws[0] + ws[1] + ws[2] + ws[3];
}

__global__ __launch_bounds__(64) void scan_mid_kernel(int* __restrict__ partial, int nb) {
    int l = threadIdx.x;
    int v = (l < nb) ? partial[l] : 0;
    int s = v;
#pragma unroll
    for (int o = 1; o < 64; o <<= 1) {
        int t = __shfl_up(s, o, 64);
        if (l >= o) s += t;
    }
    if (l < nb) partial[l] = s - v;  // exclusive
}

// cnt and cursor may alias (each element touched by exactly one thread)
__global__ __launch_bounds__(256) void scan2_kernel(const int* cnt,
                                                    const int* __restrict__ partial,
                                                    int* __restrict__ off,
                                                    int* cursor, int n) {
    __shared__ int wsum[4];
    int t = threadIdx.x;
    int lane = t & 63, wv = t >> 6;
    int i0 = blockIdx.x * 1024 + t * 4;
    int v0 = 0, v1 = 0, v2 = 0, v3 = 0;
    if (i0 + 0 < n) v0 = cnt[i0 + 0];
    if (i0 + 1 < n) v1 = cnt[i0 + 1];
    if (i0 + 2 < n) v2 = cnt[i0 + 2];
    if (i0 + 3 < n) v3 = cnt[i0 + 3];
    int s = v0 + v1 + v2 + v3;
    int sc = s;
#pragma unroll
    for (int o = 1; o < 64; o <<= 1) {
        int u = __shfl_up(sc, o, 64);
        if (lane >= o) sc += u;
    }
    if (lane == 63) wsum[wv] = sc;
    __syncthreads();
    int add = partial[blockIdx.x];
    for (int w = 0; w < wv; ++w) add += wsum[w];
    int excl = add + sc - s;
    if (i0 + 0 < n) { cursor[i0 + 0] = excl; off[i0 + 1] = excl + v0; } excl += v0;
    if (i0 + 1 < n) { cursor[i0 + 1] = excl; off[i0 + 2] = excl + v1; } excl += v1;
    if (i0 + 2 < n) { cursor[i0 + 2] = excl; off[i0 + 3] = excl + v2; } excl += v2;
    if (i0 + 3 < n) { cursor[i0 + 3] = excl; off[i0 + 4] = excl + v3; }
    if (blockIdx.x == 0 && t == 0) off[0] = 0;
}

// ---------------- bucket fill ----------------
__global__ __launch_bounds__(256) void bucket_kernel(const int* __restrict__ src,
                                                     const int* __restrict__ dst,
                                                     int* __restrict__ cursor,
                                                     int* __restrict__ csr_src, int E) {
    int e = blockIdx.x * blockDim.x + threadIdx.x;
    if (e >= E) return;
    int pos = atomicAdd(&cursor[dst[e]], 1);
    csr_src[pos] = src[e];
}

// ---------------- weight transpose + bf16 hi/lo split ----------------
// wT[c][k], k in [0,256): k<128 -> Wl[k][c], k>=128 -> Wr[k-128][c]
__global__ __launch_bounds__(256) void wsplit_kernel(const float* __restrict__ Wl,
                                                     const float* __restrict__ Wr,
                                                     unsigned short* __restrict__ hi,
                                                     unsigned short* __restrict__ lo) {
    int idx = blockIdx.x * 256 + threadIdx.x;  // 0..32767
    int k = idx >> 7;
    int c = idx & 127;
    float v = (k < 128) ? Wl[k * 128 + c] : Wr[(k - 128) * 128 + c];
    unsigned int h = f2bf_bits(v);
    float hf = __uint_as_float(h << 16);
    unsigned int l = f2bf_bits(v - hf);
    hi[c * 256 + k] = (unsigned short)h;
    lo[c * 256 + k] = (unsigned short)l;
}

// ---------------- fused gather-mean + bf16x3 MFMA GEMM ----------------
// 4 waves/block, 16 nodes/wave. Gather: 2 rows in flight per instr (half-wave
// each, float4/lane), 8x unroll -> 16 rows (8KB) outstanding. Mean -> a_sh
// (LDS transpose). GEMM: out[64][128] = [mean|x][64][256] @ wT^T via
// mfma_f32_16x16x32_bf16, bf16x3 split for ~fp32 accuracy. x-side A-frags and
// all B-frags read straight from global (L1/L2-resident), no LDS, no barriers.
__global__ __launch_bounds__(256) void sage_fused(
    const float* __restrict__ feat,
    const int* __restrict__ off,
    const int* __restrict__ csr_src,
    const unsigned short* __restrict__ wT_hi,   // [128][256]
    const unsigned short* __restrict__ wT_lo,
    const float* __restrict__ bias,
    float* __restrict__ out,
    int n_nodes, int do_relu)
{
    __shared__ float a_sh[WPB][NPW][AST];

    const int tid = threadIdx.x;
    const int wv = tid >> 6;
    const int lane = tid & 63;
    const int half = lane >> 5;
    const int l5 = lane & 31;
    const int n0w = blockIdx.x * BN + wv * NPW;

    // ---- phase A: gather-mean ----
    const float* fb = feat + (size_t)l5 * 4;
    for (int p = 0; p < 8; ++p) {
        const int j = p * 2 + half;
        const int n = n0w + j;
        f32x4 acc = {0.f, 0.f, 0.f, 0.f};
        int start = 0, end = 0;
        if (n < n_nodes) { start = off[n]; end = off[n + 1]; }
        int e = start;
        for (; e + 8 <= end; e += 8) {
            int s0 = csr_src[e + 0], s1 = csr_src[e + 1];
            int s2 = csr_src[e + 2], s3 = csr_src[e + 3];
            int s4 = csr_src[e + 4], s5 = csr_src[e + 5];
            int s6 = csr_src[e + 6], s7 = csr_src[e + 7];
            f32x4 v0 = *(const f32x4*)(fb + (size_t)s0 * D);
            f32x4 v1 = *(const f32x4*)(fb + (size_t)s1 * D);
            f32x4 v2 = *(const f32x4*)(fb + (size_t)s2 * D);
            f32x4 v3 = *(const f32x4*)(fb + (size_t)s3 * D);
            f32x4 v4 = *(const f32x4*)(fb + (size_t)s4 * D);
            f32x4 v5 = *(const f32x4*)(fb + (size_t)s5 * D);
            f32x4 v6 = *(const f32x4*)(fb + (size_t)s6 * D);
            f32x4 v7 = *(const f32x4*)(fb + (size_t)s7 * D);
            acc += ((v0 + v1) + (v2 + v3)) + ((v4 + v5) + (v6 + v7));
        }
        for (; e < end; ++e) {
            int s = csr_src[e];
            acc += *(const f32x4*)(fb + (size_t)s * D);
        }
        float dinv = 1.0f / (float)max(end - start, 1);
        acc *= dinv;
        *(f32x4*)&a_sh[wv][j][l5 * 4] = acc;
    }
    __syncthreads();

    // ---- phase B: MFMA ----
    const int q = lane >> 4;     // quad: k-group
    const int r16 = lane & 15;   // A row / B col within tile
    f32x4 acc8[8];
#pragma unroll
    for (int t = 0; t < 8; ++t) acc8[t] = (f32x4){0.f, 0.f, 0.f, 0.f};

    const int xrow = (n0w + r16 < n_nodes) ? (n0w + r16) : (n_nodes - 1);
    const float* xbase = feat + (size_t)xrow * D + q * 8;
    const float* abase = &a_sh[wv][r16][q * 8];
    const size_t wrow = (size_t)r16 * 256 + q * 8;

    for (int ks = 0; ks < 8; ++ks) {
        f32x4 a0, a1;
        if (ks < 4) {
            a0 = *(const f32x4*)(abase + ks * 32);
            a1 = *(const f32x4*)(abase + ks * 32 + 4);
        } else {
            a0 = *(const f32x4*)(xbase + (ks - 4) * 32);
            a1 = *(const f32x4*)(xbase + (ks - 4) * 32 + 4);
        }
        short8 ahi, alo;
#pragma unroll
        for (int i = 0; i < 8; ++i) {
            float v = (i < 4) ? a0[i] : a1[i - 4];
            unsigned int h = f2bf_bits(v);
            float hf = __uint_as_float(h << 16);
            unsigned int l = f2bf_bits(v - hf);
            ahi[i] = (short)h;
            alo[i] = (short)l;
        }
        const unsigned short* whp = wT_hi + wrow + ks * 32;
        const unsigned short* wlp = wT_lo + wrow + ks * 32;
#pragma unroll
        for (int t = 0; t < 8; ++t) {
            short8 bhi = *(const short8*)(whp + (size_t)t * 16 * 256);
            short8 blo = *(const short8*)(wlp + (size_t)t * 16 * 256);
            acc8[t] = __builtin_amdgcn_mfma_f32_16x16x32_bf16(ahi, bhi, acc8[t], 0, 0, 0);
            acc8[t] = __builtin_amdgcn_mfma_f32_16x16x32_bf16(alo, bhi, acc8[t], 0, 0, 0);
            acc8[t] = __builtin_amdgcn_mfma_f32_16x16x32_bf16(ahi, blo, acc8[t], 0, 0, 0);
        }
    }

    // ---- epilogue: C/D layout col=lane&15, row=quad*4+reg ----
#pragma unroll
    for (int t = 0; t < 8; ++t) {
        const float bv = bias[t * 16 + r16];
#pragma unroll
        for (int r = 0; r < 4; ++r) {
            const int node = n0w + q * 4 + r;
            if (node < n_nodes) {
                float v = acc8[t][r] + bv;
                if (do_relu) v = fmaxf(v, 0.f);
                out[(size_t)node * D + t * 16 + r16] = v;
            }
        }
    }
}

// ---------------- edge dot-product decode ----------------
__global__ __launch_bounds__(256) void pred_kernel(const float* __restrict__ z,
                                                   const int* __restrict__ ps,
                                                   const int* __restrict__ pd,
                                                   float* __restrict__ out, int EP) {
    int idx = blockIdx.x * blockDim.x + threadIdx.x;
    int e = idx >> 5;
    if (e >= EP) return;
    int l = idx & 31;
    int a = ps[e];
    int b = pd[e];
    f32x4 va = *(const f32x4*)(z + (size_t)a * D + l * 4);
    f32x4 vb = *(const f32x4*)(z + (size_t)b * D + l * 4);
    float p = va.x * vb.x + va.y * vb.y + va.z * vb.z + va.w * vb.w;
#pragma unroll
    for (int off = 16; off > 0; off >>= 1) p += __shfl_xor(p, off, 32);
    if (l == 0) out[e] = p;
}

extern "C" void kernel_launch(void* const* d_in, const int* in_sizes, int n_in,
                              void* d_out, int out_size, void* d_ws, size_t ws_size,
                              hipStream_t stream) {
    const float* x   = (const float*)d_in[0];
    const float* W1l = (const float*)d_in[1];
    const float* b1  = (const float*)d_in[2];
    const float* W1r = (const float*)d_in[3];
    const float* W2l = (const float*)d_in[4];
    const float* b2  = (const float*)d_in[5];
    const float* W2r = (const float*)d_in[6];
    const int* edge_index = (const int*)d_in[7];
    const int* pred_edges = (const int*)d_in[8];
    float* out = (float*)d_out;

    const int N  = in_sizes[0] / D;   // 50000
    const int E  = in_sizes[7] / 2;   // 800000
    const int EP = in_sizes[8] / 2;   // 200000

    const int* src = edge_index;
    const int* dst = edge_index + E;
    const int* ps  = pred_edges;
    const int* pd  = pred_edges + EP;

    // workspace layout
    int* off     = (int*)d_ws;                 // N+1 (padded 50016)
    int* cursor  = off + 50016;                // N (padded 50016)
    int* partial = cursor + 50016;             // 64
    int* csr_src = partial + 64;               // E
    float* h     = (float*)(csr_src + E);      // N*D
    float* z     = h + (size_t)N * D;          // N*D
    unsigned short* w1T_hi = (unsigned short*)(z + (size_t)N * D);
    unsigned short* w1T_lo = w1T_hi + 32768;
    unsigned short* w2T_hi = w1T_lo + 32768;
    unsigned short* w2T_lo = w2T_hi + 32768;

    const int nscan = (N + 1023) / 1024;       // 49
    const int nblk_sage = (N + BN - 1) / BN;   // 782

    // weight prep (independent of CSR)
    wsplit_kernel<<<128, 256, 0, stream>>>(W1l, W1r, w1T_hi, w1T_lo);
    wsplit_kernel<<<128, 256, 0, stream>>>(W2l, W2r, w2T_hi, w2T_lo);

    // CSR build
    zero_int_kernel<<<(N + 255) / 256, 256, 0, stream>>>(cursor, N);
    hist_kernel<<<(E + 255) / 256, 256, 0, stream>>>(dst, cursor, E);
    scan1_kernel<<<nscan, 256, 0, stream>>>(cursor, partial, N);
    scan_mid_kernel<<<1, 64, 0, stream>>>(partial, nscan);
    scan2_kernel<<<nscan, 256, 0, stream>>>(cursor, partial, off, cursor, N);
    bucket_kernel<<<(E + 255) / 256, 256, 0, stream>>>(src, dst, cursor, csr_src, E);

    // layer 1: h = relu(mean@W1l + x@W1r + b1)
    sage_fused<<<nblk_sage, 256, 0, stream>>>(x, off, csr_src, w1T_hi, w1T_lo, b1, h, N, 1);
    // layer 2: z = mean@W2l + h@W2r + b2
    sage_fused<<<nblk_sage, 256, 0, stream>>>(h, off, csr_src, w2T_hi, w2T_lo, b2, z, N, 0);
    // decode
    pred_kernel<<<(EP * 32 + 255) / 256, 256, 0, stream>>>(z, ps, pd, out, EP);
}